// Round 21
// baseline (124.004 us; speedup 1.0000x reference)
//
#include <hip/hip_runtime.h>
#include <hip/hip_bf16.h>

// Problem constants
#define B_N   4
#define CIN_  256
#define HH_   56
#define WW_   56
#define COUT_ 256
#define KK_   9
#define HW_   3136              // 56*56
#define KDIM  2304              // CIN_*KK_  (k index = kk*256 + ci)
#define NOFF  (B_N*18*HW_)      // 225792
#define NOUT  (B_N*COUT_*HW_)   // 3211264

typedef __attribute__((ext_vector_type(8))) short short8;   // 8 bf16 (4 VGPRs)
typedef __attribute__((ext_vector_type(4))) float float4v;  // MFMA accum

__device__ __forceinline__ short f2bf_bits(float v) {
    union { __hip_bfloat16 h; short s; } u;
    u.h = __float2bfloat16(v);
    return u.s;
}
__device__ __forceinline__ float bfbits2f(short s) {
    union { unsigned u; float f; } u2;
    u2.u = ((unsigned)(unsigned short)s) << 16;
    return u2.f;
}

// ---------------------------------------------------------------------------
// k_front r32: At2 role restructured — 64 blocks (was 2304), each stages a
// [16 m][64 ci][9 kk] weight slab in LDS (coalesced 576-float rows, row pad
// to 577 kills the 16-way bank conflict) and emits 18 fragment groups as
// coalesced short8 stores. Values and At2 layout identical -> bit-exact.
//   bx [0,64):        At2 (fragment-order weight, r23 layout)
//   bx [64,848):      xTb[b][pos][ci] bf16 (transposed x) — unchanged
//   bx [848,1136):    owT3 — unchanged
// ---------------------------------------------------------------------------
#define NB_AT2 64
#define NB_XT  784
#define NB_OW3 288
__global__ __launch_bounds__(256) void k_front(const float* __restrict__ x,
                                               const float* __restrict__ wgt,
                                               const float* __restrict__ ow,
                                               short* __restrict__ At2,
                                               short* __restrict__ xTb,
                                               short* __restrict__ owT3) {
    __shared__ float tile[64][65];               // xTb role (16.3 KB)
    __shared__ float slab[16*577];               // At2 role (36.9 KB, padded)
    int bx = blockIdx.x;
    int t = threadIdx.x;
    if (bx < NB_AT2) {
        int rt = bx >> 2, qq = bx & 3;           // m-tile 16-row group, ci quarter
        int c0 = qq * 64;
        // coalesced load: slab[mm][j] = wgt[((rt*16+mm)*256 + c0)*9 + j], j<576
        for (int idx = t; idx < 16*576; idx += 256) {
            int mm = idx / 576, j = idx - mm*576;
            slab[mm*577 + j] = wgt[((size_t)((rt*16 + mm)*CIN_ + c0))*9 + j];
        }
        __syncthreads();
        int wvv = t >> 6, ll = t & 63;
        int lq = ll & 15, lh = ll >> 4;
        // 18 g-groups: g = kk*8 + 2*qq + p  (kk 0..8, p 0..1)
        for (int gi = wvv; gi < 18; gi += 4) {
            int kk = gi >> 1, p = gi & 1;
            int g = kk*8 + 2*qq + p;
            int ccb = p*32 + lh*8;               // ci - c0 base for e=0
            union { short8 s8; short s[8]; } o;
            #pragma unroll
            for (int e = 0; e < 8; ++e)
                o.s[e] = f2bf_bits(slab[lq*577 + (ccb + e)*9 + kk]);
            *(short8*)(At2 + (((size_t)(rt*72 + g)*64 + ll) << 3)) = o.s8;
        }
        return;
    }
    if (bx < NB_AT2 + NB_XT) {
        int g = bx - NB_AT2;                     // 0..783
        int b = g / 196; int r = g % 196;
        int c0 = (r / 49) * 64; int p0 = (r % 49) * 64;
        int tp = t & 63;  int tc = t >> 6;
        #pragma unroll
        for (int i = 0; i < 16; ++i) {
            int ci = tc*16 + i;
            tile[ci][tp] = x[((size_t)b*CIN_ + c0 + ci)*HW_ + p0 + tp];
        }
        __syncthreads();
        #pragma unroll
        for (int i = 0; i < 16; ++i) {
            int p = tc*16 + i;
            xTb[((size_t)b*HW_ + p0 + p)*CIN_ + c0 + tp] = f2bf_bits(tile[tp][p]);
        }
        return;
    }
    {   // owT3 role
        int i = (bx - NB_AT2 - NB_XT)*256 + t;   // exactly 32*KDIM threads
        int c = i / KDIM; int r = i % KDIM;
        int kk = r >> 8;  int ci = r & 255;
        owT3[i] = (c < 18) ? f2bf_bits(ow[(size_t)(c*CIN_ + ci)*9 + kk]) : 0;
    }
}

// ---------------------------------------------------------------------------
// k_offgemm r26 (UNCHANGED): z=9 (1 kk/slice, K=256, 4 iters). 1764 blocks.
// ---------------------------------------------------------------------------
__global__ __launch_bounds__(256) void k_offgemm(const short* __restrict__ owT3,
                                                 const short* __restrict__ xTb,
                                                 float* __restrict__ pOff2) {
    __shared__ short sA[32*64];      // 4 KB, swizzled
    __shared__ short sB[64*64];      // 8 KB, swizzled
    __shared__ int   sP2[64];        // shifted-pos index per row; -1=OOB
    int t = threadIdx.x;
    int posb = blockIdx.x * 64;
    int b    = blockIdx.y;
    int ks   = blockIdx.z;           // 0..8 : kk == ks
    int kt0  = ks * 256;
    int kend = kt0 + 256;

    if (t < 64) {
        int pos = posb + t;
        int h = pos / WW_, w = pos % WW_;
        int yy = h + ks/3 - 1, xx = w + ks%3 - 1;
        bool v = (yy >= 0) && (yy < HH_) && (xx >= 0) && (xx < WW_);
        sP2[t] = v ? (yy*WW_ + xx) : -1;
    }
    __syncthreads();

    int arow = t >> 3,  aq  = t & 7;          // sA staging: 1 short8 each
    int brow = t >> 2,  bqc = (t & 3) * 2;    // sB staging: 2 short8 each

    int wv = t >> 6;
    int wm = (wv >> 1) * 16;         // m-tile: 0 or 16
    int wn = (wv & 1) * 32;          // n: 0 or 32
    int lane = t & 63;
    int lm = lane & 15;
    int qd = lane >> 4;

    float4v acc[2];
    acc[0] = (float4v)(0.f); acc[1] = (float4v)(0.f);

    const short* gA = owT3 + (size_t)arow*KDIM + aq*8;
    const short* xb = xTb + (size_t)b*HW_*CIN_;

    short* wA = sA + (((arow >> 4)*8 + aq)*16 + ((arow + 2*aq) & 15))*8;
    short* wB[2];
    #pragma unroll
    for (int j = 0; j < 2; ++j) {
        int qq = bqc + j;
        wB[j] = sB + (((brow >> 4)*8 + qq)*16 + ((brow + 2*qq) & 15))*8;
    }

    short8 pa, pb[2];
    const short8 zero8 = (short8)(0);
    int p2 = sP2[brow];              // fixed for the whole block (kk = ks)
    pa = *(const short8*)(gA + kt0);
    #pragma unroll
    for (int j = 0; j < 2; ++j) {
        int ci0 = (bqc + j)*8;
        pb[j] = (p2 >= 0) ? *(const short8*)(xb + (size_t)p2*CIN_ + ci0) : zero8;
    }

    for (int kt = kt0; kt < kend; kt += 64) {
        __syncthreads();                       // prev-iter LDS reads done
        *(short8*)wA = pa;
        #pragma unroll
        for (int j = 0; j < 2; ++j) *(short8*)wB[j] = pb[j];
        __syncthreads();
        int kt2 = kt + 64;
        if (kt2 < kend) {                      // prefetch next tiles
            pa = *(const short8*)(gA + kt2);
            int cb = kt2 & 255;
            #pragma unroll
            for (int j = 0; j < 2; ++j) {
                int ci0 = cb + (bqc + j)*8;
                pb[j] = (p2 >= 0) ? *(const short8*)(xb + (size_t)p2*CIN_ + ci0) : zero8;
            }
        }
        #pragma unroll
        for (int kss = 0; kss < 2; ++kss) {
            int qe = kss*4 + qd;
            int sw = (lm + 2*qe) & 15;
            short8 af, bf[2];
            af = *(short8*)(sA + ((((wm>>4))*8 + qe)*16 + sw)*8);
            #pragma unroll
            for (int j = 0; j < 2; ++j)
                bf[j] = *(short8*)(sB + ((((wn>>4) + j)*8 + qe)*16 + sw)*8);
            #pragma unroll
            for (int j = 0; j < 2; ++j)
                acc[j] = __builtin_amdgcn_mfma_f32_16x16x32_bf16(
                             af, bf[j], acc[j], 0, 0, 0);
        }
    }

    float* pbase = pOff2 + (size_t)ks*NOFF;
    #pragma unroll
    for (int j = 0; j < 2; ++j) {
        int col = posb + wn + j*16 + lm;
        #pragma unroll
        for (int r = 0; r < 4; ++r) {
            int c = wm + qd*4 + r;
            if (c < 18)
                pbase[((size_t)(b*18 + c))*HW_ + col] = acc[j][r];
        }
    }
}

// ---------------------------------------------------------------------------
// k_gemm (UNCHANGED from r26/r31, measured 121.6/122.4 total): M256xN32
// dedup, A-direct from At2, CGLOAD hoisted before bar1, z=3, XCD swizzle.
// ---------------------------------------------------------------------------
__global__ __launch_bounds__(256) void k_gemm(const short* __restrict__ At2,
                                              const short* __restrict__ xTb,
                                              const float* __restrict__ pOff2,
                                              const float* __restrict__ ob,
                                              float* __restrict__ pout) {
    __shared__ short sB[32*64];      // 4 KB, swizzled
    __shared__ int4   sPI[3*32];
    __shared__ float4 sPW[3*32];
    int t = threadIdx.x;

    int idx = blockIdx.x;            // 0..1175
    int xcd = idx & 7;
    int b   = xcd & 3;
    int q   = (idx >> 3)*2 + (xcd >> 2);   // 0..293
    int sidx = q % 98;
    int ks   = q / 98;               // 0..2 : kk in [ks*3, ks*3+3)
    int posb = sidx * 32;

    // ---- bilinear params (ob + 9 slice partials, fixed order) ----
    for (int e = t; e < 3*32; e += 256) {
        int kk = ks*3 + (e >> 5); int pl = e & 31;
        int pos = posb + pl;
        int h = pos / WW_, w = pos % WW_;
        size_t oy = (size_t)(b*18 + 2*kk    )*HW_ + pos;
        size_t ox = (size_t)(b*18 + 2*kk + 1)*HW_ + pos;
        float dy = ob[2*kk], dx = ob[2*kk + 1];
        #pragma unroll
        for (int s = 0; s < 9; ++s) {
            dy += pOff2[(size_t)s*NOFF + oy];
            dx += pOff2[(size_t)s*NOFF + ox];
        }
        float py = (float)(h - 1 + kk/3) + dy;
        float px = (float)(w - 1 + kk%3) + dx;
        float y0f = floorf(py), x0f = floorf(px);
        int y0 = (int)y0f, x0 = (int)x0f;
        float ty = py - y0f, tx = px - x0f;
        bool vy0 = (y0   >= 0) && (y0   < HH_);
        bool vy1 = (y0+1 >= 0) && (y0+1 < HH_);
        bool vx0 = (x0   >= 0) && (x0   < WW_);
        bool vx1 = (x0+1 >= 0) && (x0+1 < WW_);
        int y0c = min(max(y0,   0), HH_-1), y1c = min(max(y0+1, 0), HH_-1);
        int x0c = min(max(x0,   0), WW_-1), x1c = min(max(x0+1, 0), WW_-1);
        sPI[e] = make_int4(y0c*WW_+x0c, y0c*WW_+x1c, y1c*WW_+x0c, y1c*WW_+x1c);
        sPW[e] = make_float4((vy0 && vx0) ? (1.f-ty)*(1.f-tx) : 0.f,
                             (vy0 && vx1) ? (1.f-ty)*tx       : 0.f,
                             (vy1 && vx0) ? ty*(1.f-tx)       : 0.f,
                             (vy1 && vx1) ? ty*tx             : 0.f);
    }
    __syncthreads();

    int brow = t >> 3;               // B staging row 0..31
    int bq   = t & 7;                // chunk (8 shorts) 0..7

    int wv = t >> 6;                 // wave -> M strip wv*64
    int lane = t & 63;
    int lm = lane & 15;
    int qd = lane >> 4;

    float4v acc[4][2];
    #pragma unroll
    for (int i = 0; i < 4; ++i)
        #pragma unroll
        for (int j = 0; j < 2; ++j) acc[i][j] = (float4v)(0.f);

    const short* xb = xTb + (size_t)b*HW_*CIN_;
    // A fragment base: rt0 = wv*4 ; lane offset 8 shorts (16B)
    const short* pA = At2 + (((size_t)(wv*4) * 72) << 9) + (size_t)lane * 8;
    int g0 = ks * 24;                // K32-group base for this ks slice

    short* wB = sB + (((brow >> 4)*8 + bq)*16 + ((brow + 2*bq) & 15))*8;

    short8 cg[4];                    // 4-corner gather regs (1-deep, proven)
    float4 bwv;

#define CGLOAD(itX) do {                                                      \
    int4 id_ = sPI[((itX) >> 2)*32 + brow];                                   \
    bwv = sPW[((itX) >> 2)*32 + brow];                                        \
    int ci0_ = ((itX) & 3) * 64 + bq*8;                                       \
    cg[0] = *(const short8*)(xb + (size_t)id_.x*CIN_ + ci0_);                 \
    cg[1] = *(const short8*)(xb + (size_t)id_.y*CIN_ + ci0_);                 \
    cg[2] = *(const short8*)(xb + (size_t)id_.z*CIN_ + ci0_);                 \
    cg[3] = *(const short8*)(xb + (size_t)id_.w*CIN_ + ci0_);                 \
} while (0)

    CGLOAD(0);                       // prologue gather for it=0

    for (int it = 0; it < 12; ++it) {
        // issue this iter's 8 a-frag loads early (consumed after barrier 2)
        short8 af[8];
        #pragma unroll
        for (int kss = 0; kss < 2; ++kss)
            #pragma unroll
            for (int i = 0; i < 4; ++i)
                af[kss*4 + i] = *(const short8*)(
                    pA + ((size_t)(i*72 + g0 + it*2 + kss) << 9));

        // blend corners; packed bf16 cvt (1 short8 per thread)
        short8 pk;
        {
            float f[8];
            #pragma unroll
            for (int e = 0; e < 8; ++e)
                f[e] = bwv.x*bfbits2f(cg[0][e]) + bwv.y*bfbits2f(cg[1][e])
                     + bwv.z*bfbits2f(cg[2][e]) + bwv.w*bfbits2f(cg[3][e]);
            union { short8 s8; __hip_bfloat162 h2[4]; } pu;
            #pragma unroll
            for (int e2 = 0; e2 < 4; ++e2)
                pu.h2[e2] = __float22bfloat162_rn(make_float2(f[2*e2], f[2*e2+1]));
            pk = pu.s8;
        }
        // issue next gather NOW — cg regs are free after the blend, and the
        // loads fly across bar1 + sB write + bar2 + MFMA before use.
        if (it + 1 < 12) CGLOAD(it + 1);

        __syncthreads();                       // prev-iter LDS reads done
        *(short8*)wB = pk;
        __syncthreads();

        #pragma unroll
        for (int kss = 0; kss < 2; ++kss) {
            int qe = kss*4 + qd;
            int sw = (lm + 2*qe) & 15;
            short8 bf[2];
            #pragma unroll
            for (int j = 0; j < 2; ++j)
                bf[j] = *(short8*)(sB + ((j*8 + qe)*16 + sw)*8);
            #pragma unroll
            for (int i = 0; i < 4; ++i)
                #pragma unroll
                for (int j = 0; j < 2; ++j)
                    acc[i][j] = __builtin_amdgcn_mfma_f32_16x16x32_bf16(
                                    af[kss*4 + i], bf[j], acc[i][j], 0, 0, 0);
        }
    }
#undef CGLOAD

    // epilogue -> per-slice partial. C/D layout col=lane&15 (n), row=qd*4+r.
    float* pbase = pout + (size_t)ks*NOUT;
    #pragma unroll
    for (int i = 0; i < 4; ++i)
        #pragma unroll
        for (int j = 0; j < 2; ++j) {
            int col = posb + j*16 + lm;
            #pragma unroll
            for (int r = 0; r < 4; ++r) {
                int m = wv*64 + i*16 + qd*4 + r;
                pbase[((size_t)b*COUT_ + m)*HW_ + col] = acc[i][j][r];
            }
        }
}

// ---------------------------------------------------------------------------
// k_oreduce: out = p0 + p1 + p2 (fixed order, bit-exact; float4 vectorized).
// ---------------------------------------------------------------------------
__global__ __launch_bounds__(256) void k_oreduce(const float* __restrict__ pout,
                                                 float* __restrict__ out) {
    int i = blockIdx.x*256 + threadIdx.x;        // float4 index, NOUT/4 total
    if (i >= NOUT/4) return;
    float4 a = ((const float4*)pout)[i];
    float4 b = ((const float4*)(pout + NOUT))[i];
    float4 c = ((const float4*)(pout + 2*(size_t)NOUT))[i];
    float4 r;
    r.x = a.x + b.x + c.x;  r.y = a.y + b.y + c.y;
    r.z = a.z + b.z + c.z;  r.w = a.w + b.w + c.w;
    ((float4*)out)[i] = r;
}

// ---------------------------------------------------------------------------
extern "C" void kernel_launch(void* const* d_in, const int* in_sizes, int n_in,
                              void* d_out, int out_size, void* d_ws, size_t ws_size,
                              hipStream_t stream) {
    const float* x   = (const float*)d_in[0];
    const float* wgt = (const float*)d_in[1];
    const float* ow  = (const float*)d_in[2];
    const float* ob  = (const float*)d_in[3];
    float* out = (float*)d_out;

    char* ws = (char*)d_ws;
    // ws layout (16B aligned): At2 | xTb | owT3 | pOff2[9] | pout[3]  (~54MB)
    short* At2   = (short*)ws;                       // 589824*2  =  1179648
    short* xTb   = (short*)(ws + 1179648);           // 3211264*2 =  6422528
    short* owT3  = (short*)(ws + 7602176);           // 32*2304*2 =   147456
    float* pOff2 = (float*)(ws + 7749632);           // 9*225792*4=  8128512
    float* pout  = (float*)(ws + 15878144);          // 3*12845056= 38535168

    k_front  <<<dim3(NB_AT2 + NB_XT + NB_OW3), 256, 0, stream>>>(x, wgt, ow, At2, xTb, owT3);
    k_offgemm<<<dim3(49, 4, 9),               256, 0, stream>>>(owT3, xTb, pOff2);
    k_gemm   <<<dim3(1176),                   256, 0, stream>>>(At2, xTb, pOff2, ob, pout);
    k_oreduce<<<dim3(NOUT/4/256),             256, 0, stream>>>(pout, out);
}

// Round 23
// 121.264 us; speedup vs baseline: 1.0226x; 1.0226x over previous
//
#include <hip/hip_runtime.h>
#include <hip/hip_bf16.h>

// Problem constants
#define B_N   4
#define CIN_  256
#define HH_   56
#define WW_   56
#define COUT_ 256
#define KK_   9
#define HW_   3136              // 56*56
#define KDIM  2304              // CIN_*KK_  (k index = kk*256 + ci)
#define NOFF  (B_N*18*HW_)      // 225792
#define NOUT  (B_N*COUT_*HW_)   // 3211264

typedef __attribute__((ext_vector_type(8))) short short8;   // 8 bf16 (4 VGPRs)
typedef __attribute__((ext_vector_type(4))) float float4v;  // MFMA accum

__device__ __forceinline__ short f2bf_bits(float v) {
    union { __hip_bfloat16 h; short s; } u;
    u.h = __float2bfloat16(v);
    return u.s;
}
__device__ __forceinline__ float bfbits2f(short s) {
    union { unsigned u; float f; } u2;
    u2.u = ((unsigned)(unsigned short)s) << 16;
    return u2.f;
}

// ---------------------------------------------------------------------------
// FINAL (r26/r31 structure, twice-measured session best: 121.6 / 122.4 us).
// k_front: prep-only (r23 At2 fragment-order weight).
// ---------------------------------------------------------------------------
#define NB_AT  2304
#define NB_XT  784
#define NB_OW3 288
__global__ __launch_bounds__(256) void k_front(const float* __restrict__ x,
                                               const float* __restrict__ wgt,
                                               const float* __restrict__ ow,
                                               short* __restrict__ At2,
                                               short* __restrict__ xTb,
                                               short* __restrict__ owT3) {
    __shared__ float tile[64][65];
    int bx = blockIdx.x;
    int t = threadIdx.x;
    if (bx < NB_AT) {
        int i = bx*256 + t;                      // [0, 589824) = COUT_*KDIM
        int e = i & 7;
        int l = (i >> 3) & 63;
        int gg = i >> 9;                         // [0, 1152) = 16 rt * 72 g
        int g  = gg % 72;
        int rt = gg / 72;
        int m = rt*16 + (l & 15);
        int k = g*32 + (l >> 4)*8 + e;
        int kk = k >> 8;  int ci = k & 255;
        At2[i] = f2bf_bits(wgt[(size_t)(m*CIN_ + ci)*9 + kk]);
        return;
    }
    if (bx < NB_AT + NB_XT) {
        int g = bx - NB_AT;                      // 0..783
        int b = g / 196; int r = g % 196;
        int c0 = (r / 49) * 64; int p0 = (r % 49) * 64;
        int tp = t & 63;  int tc = t >> 6;
        #pragma unroll
        for (int i = 0; i < 16; ++i) {
            int ci = tc*16 + i;
            tile[ci][tp] = x[((size_t)b*CIN_ + c0 + ci)*HW_ + p0 + tp];
        }
        __syncthreads();
        #pragma unroll
        for (int i = 0; i < 16; ++i) {
            int p = tc*16 + i;
            xTb[((size_t)b*HW_ + p0 + p)*CIN_ + c0 + tp] = f2bf_bits(tile[tp][p]);
        }
        return;
    }
    {   // owT3 role
        int i = (bx - NB_AT - NB_XT)*256 + t;    // exactly 32*KDIM threads
        int c = i / KDIM; int r = i % KDIM;
        int kk = r >> 8;  int ci = r & 255;
        owT3[i] = (c < 18) ? f2bf_bits(ow[(size_t)(c*CIN_ + ci)*9 + kk]) : 0;
    }
}

// ---------------------------------------------------------------------------
// k_offgemm r26: z=9 (1 kk/slice, K=256, 4 iters). Grid (49,4,9) = 1764
// blocks = 6.9 blocks/CU. Deterministic; k_gemm sums 9 partials in order.
// ---------------------------------------------------------------------------
__global__ __launch_bounds__(256) void k_offgemm(const short* __restrict__ owT3,
                                                 const short* __restrict__ xTb,
                                                 float* __restrict__ pOff2) {
    __shared__ short sA[32*64];      // 4 KB, swizzled
    __shared__ short sB[64*64];      // 8 KB, swizzled
    __shared__ int   sP2[64];        // shifted-pos index per row; -1=OOB
    int t = threadIdx.x;
    int posb = blockIdx.x * 64;
    int b    = blockIdx.y;
    int ks   = blockIdx.z;           // 0..8 : kk == ks
    int kt0  = ks * 256;
    int kend = kt0 + 256;

    if (t < 64) {
        int pos = posb + t;
        int h = pos / WW_, w = pos % WW_;
        int yy = h + ks/3 - 1, xx = w + ks%3 - 1;
        bool v = (yy >= 0) && (yy < HH_) && (xx >= 0) && (xx < WW_);
        sP2[t] = v ? (yy*WW_ + xx) : -1;
    }
    __syncthreads();

    int arow = t >> 3,  aq  = t & 7;          // sA staging: 1 short8 each
    int brow = t >> 2,  bqc = (t & 3) * 2;    // sB staging: 2 short8 each

    int wv = t >> 6;
    int wm = (wv >> 1) * 16;         // m-tile: 0 or 16
    int wn = (wv & 1) * 32;          // n: 0 or 32
    int lane = t & 63;
    int lm = lane & 15;
    int qd = lane >> 4;

    float4v acc[2];
    acc[0] = (float4v)(0.f); acc[1] = (float4v)(0.f);

    const short* gA = owT3 + (size_t)arow*KDIM + aq*8;
    const short* xb = xTb + (size_t)b*HW_*CIN_;

    short* wA = sA + (((arow >> 4)*8 + aq)*16 + ((arow + 2*aq) & 15))*8;
    short* wB[2];
    #pragma unroll
    for (int j = 0; j < 2; ++j) {
        int qq = bqc + j;
        wB[j] = sB + (((brow >> 4)*8 + qq)*16 + ((brow + 2*qq) & 15))*8;
    }

    short8 pa, pb[2];
    const short8 zero8 = (short8)(0);
    int p2 = sP2[brow];              // fixed for the whole block (kk = ks)
    pa = *(const short8*)(gA + kt0);
    #pragma unroll
    for (int j = 0; j < 2; ++j) {
        int ci0 = (bqc + j)*8;
        pb[j] = (p2 >= 0) ? *(const short8*)(xb + (size_t)p2*CIN_ + ci0) : zero8;
    }

    for (int kt = kt0; kt < kend; kt += 64) {
        __syncthreads();                       // prev-iter LDS reads done
        *(short8*)wA = pa;
        #pragma unroll
        for (int j = 0; j < 2; ++j) *(short8*)wB[j] = pb[j];
        __syncthreads();
        int kt2 = kt + 64;
        if (kt2 < kend) {                      // prefetch next tiles
            pa = *(const short8*)(gA + kt2);
            int cb = kt2 & 255;
            #pragma unroll
            for (int j = 0; j < 2; ++j) {
                int ci0 = cb + (bqc + j)*8;
                pb[j] = (p2 >= 0) ? *(const short8*)(xb + (size_t)p2*CIN_ + ci0) : zero8;
            }
        }
        #pragma unroll
        for (int kss = 0; kss < 2; ++kss) {
            int qe = kss*4 + qd;
            int sw = (lm + 2*qe) & 15;
            short8 af, bf[2];
            af = *(short8*)(sA + ((((wm>>4))*8 + qe)*16 + sw)*8);
            #pragma unroll
            for (int j = 0; j < 2; ++j)
                bf[j] = *(short8*)(sB + ((((wn>>4) + j)*8 + qe)*16 + sw)*8);
            #pragma unroll
            for (int j = 0; j < 2; ++j)
                acc[j] = __builtin_amdgcn_mfma_f32_16x16x32_bf16(
                             af, bf[j], acc[j], 0, 0, 0);
        }
    }

    float* pbase = pOff2 + (size_t)ks*NOFF;
    #pragma unroll
    for (int j = 0; j < 2; ++j) {
        int col = posb + wn + j*16 + lm;
        #pragma unroll
        for (int r = 0; r < 4; ++r) {
            int c = wm + qd*4 + r;
            if (c < 18)
                pbase[((size_t)(b*18 + c))*HW_ + col] = acc[j][r];
        }
    }
}

// ---------------------------------------------------------------------------
// k_gemm (r26 structure, measured 121.6/122.4 total): M256xN32 dedup,
// A-direct from At2, CGLOAD hoisted before bar1, z=3 K-split, XCD swizzle.
// ---------------------------------------------------------------------------
__global__ __launch_bounds__(256) void k_gemm(const short* __restrict__ At2,
                                              const short* __restrict__ xTb,
                                              const float* __restrict__ pOff2,
                                              const float* __restrict__ ob,
                                              float* __restrict__ pout) {
    __shared__ short sB[32*64];      // 4 KB, swizzled
    __shared__ int4   sPI[3*32];
    __shared__ float4 sPW[3*32];
    int t = threadIdx.x;

    int idx = blockIdx.x;            // 0..1175
    int xcd = idx & 7;
    int b   = xcd & 3;
    int q   = (idx >> 3)*2 + (xcd >> 2);   // 0..293
    int sidx = q % 98;
    int ks   = q / 98;               // 0..2 : kk in [ks*3, ks*3+3)
    int posb = sidx * 32;

    // ---- bilinear params (ob + 9 slice partials, fixed order) ----
    for (int e = t; e < 3*32; e += 256) {
        int kk = ks*3 + (e >> 5); int pl = e & 31;
        int pos = posb + pl;
        int h = pos / WW_, w = pos % WW_;
        size_t oy = (size_t)(b*18 + 2*kk    )*HW_ + pos;
        size_t ox = (size_t)(b*18 + 2*kk + 1)*HW_ + pos;
        float dy = ob[2*kk], dx = ob[2*kk + 1];
        #pragma unroll
        for (int s = 0; s < 9; ++s) {
            dy += pOff2[(size_t)s*NOFF + oy];
            dx += pOff2[(size_t)s*NOFF + ox];
        }
        float py = (float)(h - 1 + kk/3) + dy;
        float px = (float)(w - 1 + kk%3) + dx;
        float y0f = floorf(py), x0f = floorf(px);
        int y0 = (int)y0f, x0 = (int)x0f;
        float ty = py - y0f, tx = px - x0f;
        bool vy0 = (y0   >= 0) && (y0   < HH_);
        bool vy1 = (y0+1 >= 0) && (y0+1 < HH_);
        bool vx0 = (x0   >= 0) && (x0   < WW_);
        bool vx1 = (x0+1 >= 0) && (x0+1 < WW_);
        int y0c = min(max(y0,   0), HH_-1), y1c = min(max(y0+1, 0), HH_-1);
        int x0c = min(max(x0,   0), WW_-1), x1c = min(max(x0+1, 0), WW_-1);
        sPI[e] = make_int4(y0c*WW_+x0c, y0c*WW_+x1c, y1c*WW_+x0c, y1c*WW_+x1c);
        sPW[e] = make_float4((vy0 && vx0) ? (1.f-ty)*(1.f-tx) : 0.f,
                             (vy0 && vx1) ? (1.f-ty)*tx       : 0.f,
                             (vy1 && vx0) ? ty*(1.f-tx)       : 0.f,
                             (vy1 && vx1) ? ty*tx             : 0.f);
    }
    __syncthreads();

    int brow = t >> 3;               // B staging row 0..31
    int bq   = t & 7;                // chunk (8 shorts) 0..7

    int wv = t >> 6;                 // wave -> M strip wv*64
    int lane = t & 63;
    int lm = lane & 15;
    int qd = lane >> 4;

    float4v acc[4][2];
    #pragma unroll
    for (int i = 0; i < 4; ++i)
        #pragma unroll
        for (int j = 0; j < 2; ++j) acc[i][j] = (float4v)(0.f);

    const short* xb = xTb + (size_t)b*HW_*CIN_;
    // A fragment base: rt0 = wv*4 ; lane offset 8 shorts (16B)
    const short* pA = At2 + (((size_t)(wv*4) * 72) << 9) + (size_t)lane * 8;
    int g0 = ks * 24;                // K32-group base for this ks slice

    short* wB = sB + (((brow >> 4)*8 + bq)*16 + ((brow + 2*bq) & 15))*8;

    short8 cg[4];                    // 4-corner gather regs (1-deep, proven)
    float4 bwv;

#define CGLOAD(itX) do {                                                      \
    int4 id_ = sPI[((itX) >> 2)*32 + brow];                                   \
    bwv = sPW[((itX) >> 2)*32 + brow];                                        \
    int ci0_ = ((itX) & 3) * 64 + bq*8;                                       \
    cg[0] = *(const short8*)(xb + (size_t)id_.x*CIN_ + ci0_);                 \
    cg[1] = *(const short8*)(xb + (size_t)id_.y*CIN_ + ci0_);                 \
    cg[2] = *(const short8*)(xb + (size_t)id_.z*CIN_ + ci0_);                 \
    cg[3] = *(const short8*)(xb + (size_t)id_.w*CIN_ + ci0_);                 \
} while (0)

    CGLOAD(0);                       // prologue gather for it=0

    for (int it = 0; it < 12; ++it) {
        // issue this iter's 8 a-frag loads early (consumed after barrier 2)
        short8 af[8];
        #pragma unroll
        for (int kss = 0; kss < 2; ++kss)
            #pragma unroll
            for (int i = 0; i < 4; ++i)
                af[kss*4 + i] = *(const short8*)(
                    pA + ((size_t)(i*72 + g0 + it*2 + kss) << 9));

        // blend corners; packed bf16 cvt (1 short8 per thread)
        short8 pk;
        {
            float f[8];
            #pragma unroll
            for (int e = 0; e < 8; ++e)
                f[e] = bwv.x*bfbits2f(cg[0][e]) + bwv.y*bfbits2f(cg[1][e])
                     + bwv.z*bfbits2f(cg[2][e]) + bwv.w*bfbits2f(cg[3][e]);
            union { short8 s8; __hip_bfloat162 h2[4]; } pu;
            #pragma unroll
            for (int e2 = 0; e2 < 4; ++e2)
                pu.h2[e2] = __float22bfloat162_rn(make_float2(f[2*e2], f[2*e2+1]));
            pk = pu.s8;
        }
        // issue next gather NOW — cg regs are free after the blend, and the
        // loads fly across bar1 + sB write + bar2 + MFMA before use.
        if (it + 1 < 12) CGLOAD(it + 1);

        __syncthreads();                       // prev-iter LDS reads done
        *(short8*)wB = pk;
        __syncthreads();

        #pragma unroll
        for (int kss = 0; kss < 2; ++kss) {
            int qe = kss*4 + qd;
            int sw = (lm + 2*qe) & 15;
            short8 bf[2];
            #pragma unroll
            for (int j = 0; j < 2; ++j)
                bf[j] = *(short8*)(sB + ((j*8 + qe)*16 + sw)*8);
            #pragma unroll
            for (int i = 0; i < 4; ++i)
                #pragma unroll
                for (int j = 0; j < 2; ++j)
                    acc[i][j] = __builtin_amdgcn_mfma_f32_16x16x32_bf16(
                                    af[kss*4 + i], bf[j], acc[i][j], 0, 0, 0);
        }
    }
#undef CGLOAD

    // epilogue -> per-slice partial. C/D layout col=lane&15 (n), row=qd*4+r.
    float* pbase = pout + (size_t)ks*NOUT;
    #pragma unroll
    for (int i = 0; i < 4; ++i)
        #pragma unroll
        for (int j = 0; j < 2; ++j) {
            int col = posb + j*16 + lm;
            #pragma unroll
            for (int r = 0; r < 4; ++r) {
                int m = wv*64 + i*16 + qd*4 + r;
                pbase[((size_t)b*COUT_ + m)*HW_ + col] = acc[i][j][r];
            }
        }
}

// ---------------------------------------------------------------------------
// k_oreduce: out = p0 + p1 + p2 (fixed order, bit-exact; float4 vectorized).
// ---------------------------------------------------------------------------
__global__ __launch_bounds__(256) void k_oreduce(const float* __restrict__ pout,
                                                 float* __restrict__ out) {
    int i = blockIdx.x*256 + threadIdx.x;        // float4 index, NOUT/4 total
    if (i >= NOUT/4) return;
    float4 a = ((const float4*)pout)[i];
    float4 b = ((const float4*)(pout + NOUT))[i];
    float4 c = ((const float4*)(pout + 2*(size_t)NOUT))[i];
    float4 r;
    r.x = a.x + b.x + c.x;  r.y = a.y + b.y + c.y;
    r.z = a.z + b.z + c.z;  r.w = a.w + b.w + c.w;
    ((float4*)out)[i] = r;
}

// ---------------------------------------------------------------------------
extern "C" void kernel_launch(void* const* d_in, const int* in_sizes, int n_in,
                              void* d_out, int out_size, void* d_ws, size_t ws_size,
                              hipStream_t stream) {
    const float* x   = (const float*)d_in[0];
    const float* wgt = (const float*)d_in[1];
    const float* ow  = (const float*)d_in[2];
    const float* ob  = (const float*)d_in[3];
    float* out = (float*)d_out;

    char* ws = (char*)d_ws;
    // ws layout (16B aligned): At2 | xTb | owT3 | pOff2[9] | pout[3]  (~54MB)
    short* At2   = (short*)ws;                       // 589824*2  =  1179648
    short* xTb   = (short*)(ws + 1179648);           // 3211264*2 =  6422528
    short* owT3  = (short*)(ws + 7602176);           // 32*2304*2 =   147456
    float* pOff2 = (float*)(ws + 7749632);           // 9*225792*4=  8128512
    float* pout  = (float*)(ws + 15878144);          // 3*12845056= 38535168

    k_front  <<<dim3(NB_AT + NB_XT + NB_OW3), 256, 0, stream>>>(x, wgt, ow, At2, xTb, owT3);
    k_offgemm<<<dim3(49, 4, 9),               256, 0, stream>>>(owT3, xTb, pOff2);
    k_gemm   <<<dim3(1176),                   256, 0, stream>>>(At2, xTb, pOff2, ob, pout);
    k_oreduce<<<dim3(NOUT/4/256),             256, 0, stream>>>(pout, out);
}